// Round 11
// baseline (17.293 us; speedup 1.0000x reference)
//
#include <hip/hip_runtime.h>

#define BB 256
#define PP 64
#define LL 16
#define DD 64
#define IMGF 512

__device__ __forceinline__ float wred_sum(float v) {
#pragma unroll
    for (int off = 32; off > 0; off >>= 1) v += __shfl_xor(v, off, 64);
    return v;
}

// sum across a 16-lane group (groups aligned on 16-lane boundaries)
__device__ __forceinline__ float gred_sum16(float v) {
    v += __shfl_xor(v, 1, 64);
    v += __shfl_xor(v, 2, 64);
    v += __shfl_xor(v, 4, 64);
    v += __shfl_xor(v, 8, 64);
    return v;
}

__device__ __forceinline__ float dot4(float4 a, float4 b) {
    return a.x * b.x + a.y * b.y + a.z * b.z + a.w * b.w;
}

// 1/max(sqrt(n),1e-12) ~= rsqrt(max(n,1e-24)): single v_rsq_f32, ~2ulp.
__device__ __forceinline__ float rnorm_fast(float n) {
    return rsqrtf(fmaxf(n, 1e-24f));
}

// Single fused kernel, one 1024-thread block (16 waves) per batch element b.
// All 16 meta-row gather loads are issued BEFORE the first barrier so their
// L3 latency overlaps the fq/fr staging + barrier drain + GEMV phase; the
// consume phase after GEMV reads registers only. Masked rows redirect to
// row 0 (L1-hot); mask folded multiplicatively (exact zeros).
__launch_bounds__(1024, 1)
__global__ void k_fused(const int* __restrict__ qry_id, const int* __restrict__ res_id,
                        const int* __restrict__ path, const int* __restrict__ mask,
                        const float* __restrict__ img, const float* __restrict__ Ww,
                        const float* __restrict__ Wb,
                        const float* __restrict__ meta,
                        const float* __restrict__ hw, const float* __restrict__ hb,
                        const float* __restrict__ p1w, const float* __restrict__ p1b,
                        const float* __restrict__ p2w, const float* __restrict__ p2b,
                        float* __restrict__ out) {
    __shared__ float fq[IMGF], fr[IMGF];     // staged image feature rows
    __shared__ float pq_row[DD], pr_row[DD]; // GEMV row dots (pre-norm)
    __shared__ float qf[DD], rf[DD];         // normalized features
    __shared__ float pr_sh[PP][DD];          // path_res
    __shared__ float weight_sh[PP];
    __shared__ float wsh[PP];

    int b = blockIdx.x;
    int tid = threadIdx.x;
    int lane = tid & 63;
    int wv = tid >> 6;        // 0..15
    int g = lane >> 4;        // 16-lane group in wave: 0..3
    int j = lane & 15;        // lane within group
    int p = wv * 4 + g;       // this group's path index

    // ---- load this group's path indices+mask (coalesced, 1 int/lane) ----
    int packed;
    {
        int pj = path[(b * PP + p) * LL + j];
        int mj = mask[(b * PP + p) * LL + j];
        packed = pj | (mj << 16);     // idx < 50000 < 65536
    }

    // ---- stage the two gathered image-feature rows (coalesced) ----
    {
        int qid = qry_id[b], rid = res_id[b];
        if (tid < IMGF) fq[tid] = img[(long long)qid * IMGF + tid];
        else            fr[tid - IMGF] = img[(long long)rid * IMGF + (tid - IMGF)];
    }

    // ---- issue ALL 16 meta gather loads now (overlap staging + barrier +
    //      GEMV); masked lanes redirect to row 0 which stays L1-hot ----
    float4 v[16];
#pragma unroll
    for (int l = 0; l < LL; ++l) {
        int im = __shfl(packed, (lane & 48) | l, 64);
        int idx = (im >> 16) ? (im & 0xFFFF) : 0;
        v[l] = *(const float4*)(meta + idx * DD + 4 * j);
    }
    __syncthreads();

    // ---- GEMV: group (wv,g) owns output row; contiguous float4 striding ----
    {
        int row = p;                                  // 16 waves * 4 groups = 64 rows
        const float4* wr = (const float4*)(Ww + row * IMGF);
        const float4* q4p = (const float4*)fq;
        const float4* r4p = (const float4*)fr;
        float aq = 0.f, ar = 0.f;
#pragma unroll
        for (int i = 0; i < 8; ++i) {
            float4 w4 = wr[i * 16 + j];               // group: 256B contiguous
            float4 q4 = q4p[i * 16 + j];
            float4 r4 = r4p[i * 16 + j];
            aq += dot4(w4, q4);
            ar += dot4(w4, r4);
        }
        aq = gred_sum16(aq);
        ar = gred_sum16(ar);
        if (j == 0) { pq_row[row] = aq; pr_row[row] = ar; }
    }
    __syncthreads();
    if (wv < 2) {                      // finish norms while others consume gathers
        float acc = Wb[lane] + (wv ? pr_row[lane] : pq_row[lane]);
        float n = wred_sum(acc * acc);
        float val = acc * rnorm_fast(n);
        (wv ? rf : qf)[lane] = val;
    }

    // ---- consume gathers: row norms + pairwise sums (registers only) ----
    float4 pm[8];
#pragma unroll
    for (int k = 0; k < 8; ++k) pm[k] = make_float4(0.f, 0.f, 0.f, 0.f);
#pragma unroll
    for (int l = 0; l < LL; ++l) {
        int im = __shfl(packed, (lane & 48) | l, 64);   // 1 instr; saves 16 VGPRs
        float m = (float)(im >> 16);
        float ss = gred_sum16(dot4(v[l], v[l]));
        float rn = m * rnorm_fast(ss);                  // mask folded in
        int k = l >> 1;
        pm[k].x += v[l].x * rn;
        pm[k].y += v[l].y * rn;
        pm[k].z += v[l].z * rn;
        pm[k].w += v[l].w * rn;
    }
    float4 a2 = make_float4(0.f, 0.f, 0.f, 0.f);
    float4 a3 = a2, a4 = a2;
#pragma unroll
    for (int k = 0; k < 7; ++k) {
        a2.x += pm[k].x * pm[k + 1].x; a2.y += pm[k].y * pm[k + 1].y;
        a2.z += pm[k].z * pm[k + 1].z; a2.w += pm[k].w * pm[k + 1].w;
    }
#pragma unroll
    for (int k = 0; k < 6; ++k) {
        a3.x += pm[k].x * pm[k + 1].x * pm[k + 2].x;
        a3.y += pm[k].y * pm[k + 1].y * pm[k + 2].y;
        a3.z += pm[k].z * pm[k + 1].z * pm[k + 2].z;
        a3.w += pm[k].w * pm[k + 1].w * pm[k + 2].w;
    }
#pragma unroll
    for (int k = 0; k < 5; ++k) {
        a4.x += pm[k].x * pm[k + 1].x * pm[k + 2].x * pm[k + 3].x;
        a4.y += pm[k].y * pm[k + 1].y * pm[k + 2].y * pm[k + 3].y;
        a4.z += pm[k].z * pm[k + 1].z * pm[k + 2].z * pm[k + 3].z;
        a4.w += pm[k].w * pm[k + 1].w * pm[k + 2].w * pm[k + 3].w;
    }
    a2.x *= (1.0f / 7.0f); a2.y *= (1.0f / 7.0f); a2.z *= (1.0f / 7.0f); a2.w *= (1.0f / 7.0f);
    a3.x *= (1.0f / 6.0f); a3.y *= (1.0f / 6.0f); a3.z *= (1.0f / 6.0f); a3.w *= (1.0f / 6.0f);
    a4.x *= (1.0f / 5.0f); a4.y *= (1.0f / 5.0f); a4.z *= (1.0f / 5.0f); a4.w *= (1.0f / 5.0f);
    float i2n = rnorm_fast(gred_sum16(dot4(a2, a2)));
    float i3n = rnorm_fast(gred_sum16(dot4(a3, a3)));
    float i4n = rnorm_fast(gred_sum16(dot4(a4, a4)));
    float4 pr;
    pr.x = (a2.x * i2n + a3.x * i3n + a4.x * i4n) * (1.0f / 3.0f);
    pr.y = (a2.y * i2n + a3.y * i3n + a4.y * i4n) * (1.0f / 3.0f);
    pr.z = (a2.z * i2n + a3.z * i3n + a4.z * i4n) * (1.0f / 3.0f);
    pr.w = (a2.w * i2n + a3.w * i3n + a4.w * i4n) * (1.0f / 3.0f);
    ((float4*)pr_sh[p])[j] = pr;
    __syncthreads();   // qf/rf written (wv<2 did it pre-consume) + pr_sh done

    {
        float4 q4 = ((const float4*)qf)[j];
        float4 r4 = ((const float4*)rf)[j];
        float4 h0 = ((const float4*)hw)[j];
        float4 h1 = ((const float4*)(hw + DD))[j];
        float t = -(q4.x - r4.x) * pr.x * h0.x + (q4.x * r4.x) * h1.x
                  - (q4.y - r4.y) * pr.y * h0.y + (q4.y * r4.y) * h1.y
                  - (q4.z - r4.z) * pr.z * h0.z + (q4.z * r4.z) * h1.z
                  - (q4.w - r4.w) * pr.w * h0.w + (q4.w * r4.w) * h1.w;
        t = gred_sum16(t);
        if (j == 0) weight_sh[p] = t;
    }
    __syncthreads();

    // ---- finale: wave 0 does softmax over P, pooled, scores ----
    if (wv == 0) {
        float wt = (weight_sh[lane] + hb[0]) * 5.0f;   // /0.2
        float mx = wt;
#pragma unroll
        for (int off = 32; off > 0; off >>= 1) mx = fmaxf(mx, __shfl_xor(mx, off, 64));
        float e = __expf(wt - mx);
        float wn = e / wred_sum(e);
        wsh[lane] = wn;
        float pooled = 0.f;
#pragma unroll 8
        for (int pp2 = 0; pp2 < PP; ++pp2) pooled += pr_sh[pp2][lane] * wsh[pp2];
        float qv = qf[lane], rv = rf[lane];
        float s1 = wred_sum(qv * rv * p1w[lane]);
        float s2 = wred_sum((rv - qv) * pooled * p2w[lane]);
        if (lane == 0) out[b] = (s1 + p1b[0]) + 5.0f * (s2 + p2b[0]);
    }
}

extern "C" void kernel_launch(void* const* d_in, const int* in_sizes, int n_in,
                              void* d_out, int out_size, void* d_ws, size_t ws_size,
                              hipStream_t stream) {
    const int*   qry_id = (const int*)d_in[0];
    const int*   res_id = (const int*)d_in[1];
    const int*   path   = (const int*)d_in[2];
    const int*   mask   = (const int*)d_in[3];
    const float* img    = (const float*)d_in[4];
    const float* Ww     = (const float*)d_in[5];
    const float* Wb     = (const float*)d_in[6];
    const float* meta   = (const float*)d_in[7];
    const float* hw     = (const float*)d_in[8];
    const float* hb     = (const float*)d_in[9];
    const float* p1w    = (const float*)d_in[10];
    const float* p1b    = (const float*)d_in[11];
    const float* p2w    = (const float*)d_in[12];
    const float* p2b    = (const float*)d_in[13];

    float* out = (float*)d_out;

    hipLaunchKernelGGL(k_fused, dim3(BB), dim3(1024), 0, stream,
                       qry_id, res_id, path, mask, img, Ww, Wb, meta,
                       hw, hb, p1w, p1b, p2w, p2b, out);
}

// Round 12
// 16.632 us; speedup vs baseline: 1.0397x; 1.0397x over previous
//
#include <hip/hip_runtime.h>

#define BB 256
#define PP 64
#define LL 16
#define DD 64
#define IMGF 512

__device__ __forceinline__ float wred_sum(float v) {
#pragma unroll
    for (int off = 32; off > 0; off >>= 1) v += __shfl_xor(v, off, 64);
    return v;
}

// sum across a 16-lane group (groups aligned on 16-lane boundaries)
__device__ __forceinline__ float gred_sum16(float v) {
    v += __shfl_xor(v, 1, 64);
    v += __shfl_xor(v, 2, 64);
    v += __shfl_xor(v, 4, 64);
    v += __shfl_xor(v, 8, 64);
    return v;
}

__device__ __forceinline__ float dot4(float4 a, float4 b) {
    return a.x * b.x + a.y * b.y + a.z * b.z + a.w * b.w;
}

// 1/max(sqrt(n),1e-12) ~= rsqrt(max(n,1e-24)): single v_rsq_f32, ~2ulp.
__device__ __forceinline__ float rnorm_fast(float n) {
    return rsqrtf(fmaxf(n, 1e-24f));
}

// Single fused kernel, one 1024-thread block (16 waves) per batch element b.
// No staging barrier: GEMV reads the two img rows directly (all groups read
// the same 2KB rows -> L1 broadcast). Gathers: all 16 issued back-to-back
// AFTER the GEMV barrier (regs never live across GEMV; one L3 round-trip).
// Masked rows redirect to row 0 (L1-hot); mask folded multiplicatively.
__launch_bounds__(1024, 1)
__global__ void k_fused(const int* __restrict__ qry_id, const int* __restrict__ res_id,
                        const int* __restrict__ path, const int* __restrict__ mask,
                        const float* __restrict__ img, const float* __restrict__ Ww,
                        const float* __restrict__ Wb,
                        const float* __restrict__ meta,
                        const float* __restrict__ hw, const float* __restrict__ hb,
                        const float* __restrict__ p1w, const float* __restrict__ p1b,
                        const float* __restrict__ p2w, const float* __restrict__ p2b,
                        float* __restrict__ out) {
    __shared__ float pq_row[DD], pr_row[DD]; // GEMV row dots (pre-norm)
    __shared__ float qf[DD], rf[DD];         // normalized features
    __shared__ float pr_sh[PP][DD];          // path_res
    __shared__ float weight_sh[PP];
    __shared__ float wsh[PP];

    int b = blockIdx.x;
    int tid = threadIdx.x;
    int lane = tid & 63;
    int wv = tid >> 6;        // 0..15
    int g = lane >> 4;        // 16-lane group in wave: 0..3
    int j = lane & 15;        // lane within group
    int p = wv * 4 + g;       // this group's path index

    // ---- load this group's path indices+mask (coalesced, 1 int/lane) ----
    int packed;
    {
        int pj = path[(b * PP + p) * LL + j];
        int mj = mask[(b * PP + p) * LL + j];
        packed = pj | (mj << 16);     // idx < 50000 < 65536
    }

    // ---- GEMV straight from global: group owns output row p; img rows are
    //      block-uniform -> L1 broadcast after first touch ----
    {
        int qid = qry_id[b], rid = res_id[b];
        const float4* wr   = (const float4*)(Ww + p * IMGF);
        const float4* qrow = (const float4*)(img + (long long)qid * IMGF);
        const float4* rrow = (const float4*)(img + (long long)rid * IMGF);
        float aq = 0.f, ar = 0.f;
#pragma unroll
        for (int i = 0; i < 8; ++i) {
            float4 w4 = wr[i * 16 + j];               // group: 256B contiguous
            aq += dot4(w4, qrow[i * 16 + j]);
            ar += dot4(w4, rrow[i * 16 + j]);
        }
        aq = gred_sum16(aq);
        ar = gred_sum16(ar);
        if (j == 0) { pq_row[p] = aq; pr_row[p] = ar; }
    }
    __syncthreads();
    if (wv < 2) {                      // finish norms while others issue gathers
        float acc = Wb[lane] + (wv ? pr_row[lane] : pq_row[lane]);
        float n = wred_sum(acc * acc);
        float val = acc * rnorm_fast(n);
        (wv ? rf : qf)[lane] = val;
    }

    // ---- issue ALL 16 meta gathers back-to-back, then consume ----
    float4 v[16];
#pragma unroll
    for (int l = 0; l < LL; ++l) {
        int im = __shfl(packed, (lane & 48) | l, 64);
        int idx = (im >> 16) ? (im & 0xFFFF) : 0;   // masked -> row 0 (L1-hot)
        v[l] = *(const float4*)(meta + idx * DD + 4 * j);
    }

    float4 pm[8];
#pragma unroll
    for (int k = 0; k < 8; ++k) pm[k] = make_float4(0.f, 0.f, 0.f, 0.f);
#pragma unroll
    for (int l = 0; l < LL; ++l) {
        int im = __shfl(packed, (lane & 48) | l, 64);   // recompute: saves regs
        float m = (float)(im >> 16);
        float ss = gred_sum16(dot4(v[l], v[l]));
        float rn = m * rnorm_fast(ss);                  // mask folded in
        int k = l >> 1;
        pm[k].x += v[l].x * rn;
        pm[k].y += v[l].y * rn;
        pm[k].z += v[l].z * rn;
        pm[k].w += v[l].w * rn;
    }
    float4 a2 = make_float4(0.f, 0.f, 0.f, 0.f);
    float4 a3 = a2, a4 = a2;
#pragma unroll
    for (int k = 0; k < 7; ++k) {
        a2.x += pm[k].x * pm[k + 1].x; a2.y += pm[k].y * pm[k + 1].y;
        a2.z += pm[k].z * pm[k + 1].z; a2.w += pm[k].w * pm[k + 1].w;
    }
#pragma unroll
    for (int k = 0; k < 6; ++k) {
        a3.x += pm[k].x * pm[k + 1].x * pm[k + 2].x;
        a3.y += pm[k].y * pm[k + 1].y * pm[k + 2].y;
        a3.z += pm[k].z * pm[k + 1].z * pm[k + 2].z;
        a3.w += pm[k].w * pm[k + 1].w * pm[k + 2].w;
    }
#pragma unroll
    for (int k = 0; k < 5; ++k) {
        a4.x += pm[k].x * pm[k + 1].x * pm[k + 2].x * pm[k + 3].x;
        a4.y += pm[k].y * pm[k + 1].y * pm[k + 2].y * pm[k + 3].y;
        a4.z += pm[k].z * pm[k + 1].z * pm[k + 2].z * pm[k + 3].z;
        a4.w += pm[k].w * pm[k + 1].w * pm[k + 2].w * pm[k + 3].w;
    }
    a2.x *= (1.0f / 7.0f); a2.y *= (1.0f / 7.0f); a2.z *= (1.0f / 7.0f); a2.w *= (1.0f / 7.0f);
    a3.x *= (1.0f / 6.0f); a3.y *= (1.0f / 6.0f); a3.z *= (1.0f / 6.0f); a3.w *= (1.0f / 6.0f);
    a4.x *= (1.0f / 5.0f); a4.y *= (1.0f / 5.0f); a4.z *= (1.0f / 5.0f); a4.w *= (1.0f / 5.0f);
    float i2n = rnorm_fast(gred_sum16(dot4(a2, a2)));
    float i3n = rnorm_fast(gred_sum16(dot4(a3, a3)));
    float i4n = rnorm_fast(gred_sum16(dot4(a4, a4)));
    float4 pr;
    pr.x = (a2.x * i2n + a3.x * i3n + a4.x * i4n) * (1.0f / 3.0f);
    pr.y = (a2.y * i2n + a3.y * i3n + a4.y * i4n) * (1.0f / 3.0f);
    pr.z = (a2.z * i2n + a3.z * i3n + a4.z * i4n) * (1.0f / 3.0f);
    pr.w = (a2.w * i2n + a3.w * i3n + a4.w * i4n) * (1.0f / 3.0f);
    ((float4*)pr_sh[p])[j] = pr;
    __syncthreads();   // qf/rf written (wv<2 did it pre-consume) + pr_sh done

    {
        float4 q4 = ((const float4*)qf)[j];
        float4 r4 = ((const float4*)rf)[j];
        float4 h0 = ((const float4*)hw)[j];
        float4 h1 = ((const float4*)(hw + DD))[j];
        float t = -(q4.x - r4.x) * pr.x * h0.x + (q4.x * r4.x) * h1.x
                  - (q4.y - r4.y) * pr.y * h0.y + (q4.y * r4.y) * h1.y
                  - (q4.z - r4.z) * pr.z * h0.z + (q4.z * r4.z) * h1.z
                  - (q4.w - r4.w) * pr.w * h0.w + (q4.w * r4.w) * h1.w;
        t = gred_sum16(t);
        if (j == 0) weight_sh[p] = t;
    }
    __syncthreads();

    // ---- finale: wave 0 does softmax over P, pooled, scores ----
    if (wv == 0) {
        float wt = (weight_sh[lane] + hb[0]) * 5.0f;   // /0.2
        float mx = wt;
#pragma unroll
        for (int off = 32; off > 0; off >>= 1) mx = fmaxf(mx, __shfl_xor(mx, off, 64));
        float e = __expf(wt - mx);
        float wn = e / wred_sum(e);
        wsh[lane] = wn;
        float pooled = 0.f;
#pragma unroll 8
        for (int pp2 = 0; pp2 < PP; ++pp2) pooled += pr_sh[pp2][lane] * wsh[pp2];
        float qv = qf[lane], rv = rf[lane];
        float s1 = wred_sum(qv * rv * p1w[lane]);
        float s2 = wred_sum((rv - qv) * pooled * p2w[lane]);
        if (lane == 0) out[b] = (s1 + p1b[0]) + 5.0f * (s2 + p2b[0]);
    }
}

extern "C" void kernel_launch(void* const* d_in, const int* in_sizes, int n_in,
                              void* d_out, int out_size, void* d_ws, size_t ws_size,
                              hipStream_t stream) {
    const int*   qry_id = (const int*)d_in[0];
    const int*   res_id = (const int*)d_in[1];
    const int*   path   = (const int*)d_in[2];
    const int*   mask   = (const int*)d_in[3];
    const float* img    = (const float*)d_in[4];
    const float* Ww     = (const float*)d_in[5];
    const float* Wb     = (const float*)d_in[6];
    const float* meta   = (const float*)d_in[7];
    const float* hw     = (const float*)d_in[8];
    const float* hb     = (const float*)d_in[9];
    const float* p1w    = (const float*)d_in[10];
    const float* p1b    = (const float*)d_in[11];
    const float* p2w    = (const float*)d_in[12];
    const float* p2b    = (const float*)d_in[13];

    float* out = (float*)d_out;

    hipLaunchKernelGGL(k_fused, dim3(BB), dim3(1024), 0, stream,
                       qry_id, res_id, path, mask, img, Ww, Wb, meta,
                       hw, hb, p1w, p1b, p2w, p2b, out);
}

// Round 13
// 15.740 us; speedup vs baseline: 1.0986x; 1.0566x over previous
//
#include <hip/hip_runtime.h>

#define BB 256
#define PP 64
#define LL 16
#define DD 64
#define IMGF 512

__device__ __forceinline__ float wred_sum(float v) {
#pragma unroll
    for (int off = 32; off > 0; off >>= 1) v += __shfl_xor(v, off, 64);
    return v;
}

// sum across a 16-lane group (groups aligned on 16-lane boundaries)
__device__ __forceinline__ float gred_sum16(float v) {
    v += __shfl_xor(v, 1, 64);
    v += __shfl_xor(v, 2, 64);
    v += __shfl_xor(v, 4, 64);
    v += __shfl_xor(v, 8, 64);
    return v;
}

__device__ __forceinline__ float dot4(float4 a, float4 b) {
    return a.x * b.x + a.y * b.y + a.z * b.z + a.w * b.w;
}

// 1/max(sqrt(n),1e-12) ~= rsqrt(max(n,1e-24)): single v_rsq_f32, ~2ulp.
__device__ __forceinline__ float rnorm_fast(float n) {
    return rsqrtf(fmaxf(n, 1e-24f));
}

// One 1024-thread block (16 waves) per batch element b. PATH-FIRST order:
// the long-latency meta gathers are issued at kernel start (overlapping the
// img staging relay, which is issued before them so its LDS-write wait
// doesn't drain the gather queue); GEMV (LDS-staged, R10-style) runs after.
// qf/rf norms are recomputed redundantly per wave (kills a barrier + LDS
// round-trip). Masked rows redirect to row 0 (L1-hot); mask folded in.
__launch_bounds__(1024, 1)
__global__ void k_fused(const int* __restrict__ qry_id, const int* __restrict__ res_id,
                        const int* __restrict__ path, const int* __restrict__ mask,
                        const float* __restrict__ img, const float* __restrict__ Ww,
                        const float* __restrict__ Wb,
                        const float* __restrict__ meta,
                        const float* __restrict__ hw, const float* __restrict__ hb,
                        const float* __restrict__ p1w, const float* __restrict__ p1b,
                        const float* __restrict__ p2w, const float* __restrict__ p2b,
                        float* __restrict__ out) {
    __shared__ float fqfr[2 * IMGF];         // staged img rows: fq | fr
    __shared__ float pq_row[DD], pr_row[DD]; // GEMV row dots (pre-norm)
    __shared__ float pr_sh[PP][DD];          // path_res (for finale pooled)
    __shared__ float weight_sh[PP];
    __shared__ float wsh[PP];

    int b = blockIdx.x;
    int tid = threadIdx.x;
    int lane = tid & 63;
    int wv = tid >> 6;        // 0..15
    int g = lane >> 4;        // 16-lane group in wave: 0..3
    int j = lane & 15;        // lane within group
    int p = wv * 4 + g;       // this group's path index

    // ---- issue all long-latency loads up front ----
    int pj = path[(b * PP + p) * LL + j];
    int mj = mask[(b * PP + p) * LL + j];
    int qid = qry_id[b], rid = res_id[b];
    int packed = pj | (mj << 16);            // idx < 50000 < 65536

    // staging relay (1 float/thread) -- issued BEFORE gathers so its
    // LDS-write waitcnt doesn't have to drain the gather queue
    float stg = (tid < IMGF) ? img[(long long)qid * IMGF + tid]
                             : img[(long long)rid * IMGF + (tid - IMGF)];

    // all 16 meta gathers back-to-back; masked -> row 0 (L1-hot dummy)
    float4 v[16];
#pragma unroll
    for (int l = 0; l < LL; ++l) {
        int im = __shfl(packed, (lane & 48) | l, 64);
        int idx = (im >> 16) ? (im & 0xFFFF) : 0;
        v[l] = *(const float4*)(meta + idx * DD + 4 * j);
    }

    fqfr[tid] = stg;                         // staging -> LDS

    // ---- consume gathers: row norms + pairwise sums (registers only) ----
    float4 pm[8];
#pragma unroll
    for (int k = 0; k < 8; ++k) pm[k] = make_float4(0.f, 0.f, 0.f, 0.f);
#pragma unroll
    for (int l = 0; l < LL; ++l) {
        int im = __shfl(packed, (lane & 48) | l, 64);   // recompute: saves regs
        float m = (float)(im >> 16);
        float ss = gred_sum16(dot4(v[l], v[l]));
        float rn = m * rnorm_fast(ss);                  // mask folded in
        int k = l >> 1;
        pm[k].x += v[l].x * rn;
        pm[k].y += v[l].y * rn;
        pm[k].z += v[l].z * rn;
        pm[k].w += v[l].w * rn;
    }
    float4 a2 = make_float4(0.f, 0.f, 0.f, 0.f);
    float4 a3 = a2, a4 = a2;
#pragma unroll
    for (int k = 0; k < 7; ++k) {
        a2.x += pm[k].x * pm[k + 1].x; a2.y += pm[k].y * pm[k + 1].y;
        a2.z += pm[k].z * pm[k + 1].z; a2.w += pm[k].w * pm[k + 1].w;
    }
#pragma unroll
    for (int k = 0; k < 6; ++k) {
        a3.x += pm[k].x * pm[k + 1].x * pm[k + 2].x;
        a3.y += pm[k].y * pm[k + 1].y * pm[k + 2].y;
        a3.z += pm[k].z * pm[k + 1].z * pm[k + 2].z;
        a3.w += pm[k].w * pm[k + 1].w * pm[k + 2].w;
    }
#pragma unroll
    for (int k = 0; k < 5; ++k) {
        a4.x += pm[k].x * pm[k + 1].x * pm[k + 2].x * pm[k + 3].x;
        a4.y += pm[k].y * pm[k + 1].y * pm[k + 2].y * pm[k + 3].y;
        a4.z += pm[k].z * pm[k + 1].z * pm[k + 2].z * pm[k + 3].z;
        a4.w += pm[k].w * pm[k + 1].w * pm[k + 2].w * pm[k + 3].w;
    }
    a2.x *= (1.0f / 7.0f); a2.y *= (1.0f / 7.0f); a2.z *= (1.0f / 7.0f); a2.w *= (1.0f / 7.0f);
    a3.x *= (1.0f / 6.0f); a3.y *= (1.0f / 6.0f); a3.z *= (1.0f / 6.0f); a3.w *= (1.0f / 6.0f);
    a4.x *= (1.0f / 5.0f); a4.y *= (1.0f / 5.0f); a4.z *= (1.0f / 5.0f); a4.w *= (1.0f / 5.0f);
    float i2n = rnorm_fast(gred_sum16(dot4(a2, a2)));
    float i3n = rnorm_fast(gred_sum16(dot4(a3, a3)));
    float i4n = rnorm_fast(gred_sum16(dot4(a4, a4)));
    float4 pr;
    pr.x = (a2.x * i2n + a3.x * i3n + a4.x * i4n) * (1.0f / 3.0f);
    pr.y = (a2.y * i2n + a3.y * i3n + a4.y * i4n) * (1.0f / 3.0f);
    pr.z = (a2.z * i2n + a3.z * i3n + a4.z * i4n) * (1.0f / 3.0f);
    pr.w = (a2.w * i2n + a3.w * i3n + a4.w * i4n) * (1.0f / 3.0f);
    ((float4*)pr_sh[p])[j] = pr;
    __syncthreads();                         // bar1: fqfr + pr_sh complete

    // ---- GEMV from LDS: group (wv,g) owns output row p ----
    {
        const float4* wr  = (const float4*)(Ww + p * IMGF);
        const float4* q4p = (const float4*)fqfr;
        const float4* r4p = (const float4*)(fqfr + IMGF);
        float aq = 0.f, ar = 0.f;
#pragma unroll
        for (int i = 0; i < 8; ++i) {
            float4 w4 = wr[i * 16 + j];      // group: 256B contiguous
            aq += dot4(w4, q4p[i * 16 + j]);
            ar += dot4(w4, r4p[i * 16 + j]);
        }
        aq = gred_sum16(aq);
        ar = gred_sum16(ar);
        if (j == 0) { pq_row[p] = aq; pr_row[p] = ar; }
    }
    __syncthreads();                         // bar2: pq_row/pr_row complete

    // ---- redundant per-wave qf/rf norms (per-lane layout, dim = lane) ----
    float accq = Wb[lane] + pq_row[lane];
    float accr = Wb[lane] + pr_row[lane];
    float qv = accq * rnorm_fast(wred_sum(accq * accq));
    float rv = accr * rnorm_fast(wred_sum(accr * accr));

    // ---- weight: relayout qv/rv to group float4 via 8 shfls ----
    {
        float4 q4, r4;
        q4.x = __shfl(qv, 4 * j, 64);     r4.x = __shfl(rv, 4 * j, 64);
        q4.y = __shfl(qv, 4 * j + 1, 64); r4.y = __shfl(rv, 4 * j + 1, 64);
        q4.z = __shfl(qv, 4 * j + 2, 64); r4.z = __shfl(rv, 4 * j + 2, 64);
        q4.w = __shfl(qv, 4 * j + 3, 64); r4.w = __shfl(rv, 4 * j + 3, 64);
        float4 h0 = ((const float4*)hw)[j];
        float4 h1 = ((const float4*)(hw + DD))[j];
        float t = -(q4.x - r4.x) * pr.x * h0.x + (q4.x * r4.x) * h1.x
                  - (q4.y - r4.y) * pr.y * h0.y + (q4.y * r4.y) * h1.y
                  - (q4.z - r4.z) * pr.z * h0.z + (q4.z * r4.z) * h1.z
                  - (q4.w - r4.w) * pr.w * h0.w + (q4.w * r4.w) * h1.w;
        t = gred_sum16(t);
        if (j == 0) weight_sh[p] = t;
    }
    __syncthreads();                         // bar3: weight_sh complete

    // ---- finale: wave 0 does softmax over P, pooled, scores ----
    if (wv == 0) {
        float wt = (weight_sh[lane] + hb[0]) * 5.0f;   // /0.2
        float mx = wt;
#pragma unroll
        for (int off = 32; off > 0; off >>= 1) mx = fmaxf(mx, __shfl_xor(mx, off, 64));
        float e = __expf(wt - mx);
        float wn = e / wred_sum(e);
        wsh[lane] = wn;
        float pooled = 0.f;
#pragma unroll 8
        for (int pp2 = 0; pp2 < PP; ++pp2) pooled += pr_sh[pp2][lane] * wsh[pp2];
        float s1 = wred_sum(qv * rv * p1w[lane]);
        float s2 = wred_sum((rv - qv) * pooled * p2w[lane]);
        if (lane == 0) out[b] = (s1 + p1b[0]) + 5.0f * (s2 + p2b[0]);
    }
}

extern "C" void kernel_launch(void* const* d_in, const int* in_sizes, int n_in,
                              void* d_out, int out_size, void* d_ws, size_t ws_size,
                              hipStream_t stream) {
    const int*   qry_id = (const int*)d_in[0];
    const int*   res_id = (const int*)d_in[1];
    const int*   path   = (const int*)d_in[2];
    const int*   mask   = (const int*)d_in[3];
    const float* img    = (const float*)d_in[4];
    const float* Ww     = (const float*)d_in[5];
    const float* Wb     = (const float*)d_in[6];
    const float* meta   = (const float*)d_in[7];
    const float* hw     = (const float*)d_in[8];
    const float* hb     = (const float*)d_in[9];
    const float* p1w    = (const float*)d_in[10];
    const float* p1b    = (const float*)d_in[11];
    const float* p2w    = (const float*)d_in[12];
    const float* p2b    = (const float*)d_in[13];

    float* out = (float*)d_out;

    hipLaunchKernelGGL(k_fused, dim3(BB), dim3(1024), 0, stream,
                       qry_id, res_id, path, mask, img, Ww, Wb, meta,
                       hw, hb, p1w, p1b, p2w, p2b, out);
}

// Round 14
// 14.235 us; speedup vs baseline: 1.2148x; 1.1057x over previous
//
#include <hip/hip_runtime.h>

#define BB 256
#define PP 64
#define LL 16
#define DD 64
#define IMGF 512

__device__ __forceinline__ float wred_sum(float v) {
#pragma unroll
    for (int off = 32; off > 0; off >>= 1) v += __shfl_xor(v, off, 64);
    return v;
}

// sum across a 16-lane group (groups aligned on 16-lane boundaries)
__device__ __forceinline__ float gred_sum16(float v) {
    v += __shfl_xor(v, 1, 64);
    v += __shfl_xor(v, 2, 64);
    v += __shfl_xor(v, 4, 64);
    v += __shfl_xor(v, 8, 64);
    return v;
}

__device__ __forceinline__ float dot4(float4 a, float4 b) {
    return a.x * b.x + a.y * b.y + a.z * b.z + a.w * b.w;
}

// 1/max(sqrt(n),1e-12) ~= rsqrt(max(n,1e-24)): single v_rsq_f32, ~2ulp.
__device__ __forceinline__ float rnorm_fast(float n) {
    return rsqrtf(fmaxf(n, 1e-24f));
}

// R9 structure (best known) + VALU cuts:
//  - row-norm via 16->1 reduce-scatter (lane j owns row j), 1 rsqrt/lane
//  - i2/i3/i4 via t[k]=pm[k]*pm[k+1] factorization
// One 1024-thread block (16 waves) per b; group (wv,g) owns path p.
__launch_bounds__(1024, 1)
__global__ void k_fused(const int* __restrict__ qry_id, const int* __restrict__ res_id,
                        const int* __restrict__ path, const int* __restrict__ mask,
                        const float* __restrict__ img, const float* __restrict__ Ww,
                        const float* __restrict__ Wb,
                        const float* __restrict__ meta,
                        const float* __restrict__ hw, const float* __restrict__ hb,
                        const float* __restrict__ p1w, const float* __restrict__ p1b,
                        const float* __restrict__ p2w, const float* __restrict__ p2b,
                        float* __restrict__ out) {
    __shared__ float fq[IMGF], fr[IMGF];     // staged image feature rows
    __shared__ float pq_row[DD], pr_row[DD]; // GEMV row dots (pre-norm)
    __shared__ float qf[DD], rf[DD];         // normalized features
    __shared__ float pr_sh[PP][DD];          // path_res
    __shared__ float weight_sh[PP];
    __shared__ float wsh[PP];

    int b = blockIdx.x;
    int tid = threadIdx.x;
    int lane = tid & 63;
    int wv = tid >> 6;        // 0..15
    int g = lane >> 4;        // 16-lane group in wave: 0..3
    int j = lane & 15;        // lane within group
    int p = wv * 4 + g;       // this group's path index

    // ---- load this group's path indices+mask (coalesced, 1 int/lane) ----
    int packed;
    {
        int pj = path[(b * PP + p) * LL + j];
        int mj = mask[(b * PP + p) * LL + j];
        packed = pj | (mj << 16);     // idx < 50000 < 65536
    }

    // ---- stage the two gathered image-feature rows (coalesced) ----
    {
        int qid = qry_id[b], rid = res_id[b];
        if (tid < IMGF) fq[tid] = img[(long long)qid * IMGF + tid];
        else            fr[tid - IMGF] = img[(long long)rid * IMGF + (tid - IMGF)];
    }
    __syncthreads();

    // ---- GEMV: group (wv,g) owns output row p; contiguous float4 striding ----
    {
        const float4* wr = (const float4*)(Ww + p * IMGF);
        const float4* q4p = (const float4*)fq;
        const float4* r4p = (const float4*)fr;
        float aq = 0.f, ar = 0.f;
#pragma unroll
        for (int i = 0; i < 8; ++i) {
            float4 w4 = wr[i * 16 + j];               // group: 256B contiguous
            aq += dot4(w4, q4p[i * 16 + j]);
            ar += dot4(w4, r4p[i * 16 + j]);
        }
        aq = gred_sum16(aq);
        ar = gred_sum16(ar);
        if (j == 0) { pq_row[p] = aq; pr_row[p] = ar; }
    }
    __syncthreads();
    if (wv < 2) {                      // finish norms while others issue gathers
        float acc = Wb[lane] + (wv ? pr_row[lane] : pq_row[lane]);
        float n = wred_sum(acc * acc);
        float val = acc * rnorm_fast(n);
        (wv ? rf : qf)[lane] = val;
    }

    // ---- path: issue all 16 gathers; per-lane partial sumsq per row ----
    float4 v[16];
#pragma unroll
    for (int l = 0; l < LL; ++l) {
        int im = __shfl(packed, (lane & 48) | l, 64);
        int idx = (im >> 16) ? (im & 0xFFFF) : 0;   // masked -> row 0 (L1-hot)
        v[l] = *(const float4*)(meta + idx * DD + 4 * j);
    }
    float ss[16];
#pragma unroll
    for (int l = 0; l < LL; ++l) ss[l] = dot4(v[l], v[l]);

    // ---- reduce-scatter across the 16-lane group: lane j <- total of row j ----
    float s8[8];
    {
        bool hi = (lane & 8) != 0;
#pragma unroll
        for (int i = 0; i < 8; ++i) {
            float snd = hi ? ss[i] : ss[i + 8];
            float kp  = hi ? ss[i + 8] : ss[i];
            s8[i] = kp + __shfl_xor(snd, 8, 64);
        }
    }
    float s4[4];
    {
        bool hi = (lane & 4) != 0;
#pragma unroll
        for (int i = 0; i < 4; ++i) {
            float snd = hi ? s8[i] : s8[i + 4];
            float kp  = hi ? s8[i + 4] : s8[i];
            s4[i] = kp + __shfl_xor(snd, 4, 64);
        }
    }
    float s2[2];
    {
        bool hi = (lane & 2) != 0;
#pragma unroll
        for (int i = 0; i < 2; ++i) {
            float snd = hi ? s4[i] : s4[i + 2];
            float kp  = hi ? s4[i + 2] : s4[i];
            s2[i] = kp + __shfl_xor(snd, 2, 64);
        }
    }
    float S;
    {
        bool hi = (lane & 1) != 0;
        float snd = hi ? s2[0] : s2[1];
        float kp  = hi ? s2[1] : s2[0];
        S = kp + __shfl_xor(snd, 1, 64);
    }
    // lane j now holds ||row j||^2 of its group; its own packed IS row j
    float mr_j = (float)(packed >> 16) * rnorm_fast(S);

    // ---- pm[k] = norm'd row 2k + norm'd row 2k+1 (pair-broadcast mr) ----
    float4 pm[8];
#pragma unroll
    for (int k = 0; k < 8; ++k) {
        float mr0 = __shfl(mr_j, (lane & 48) | (2 * k), 64);
        float mr1 = __shfl(mr_j, (lane & 48) | (2 * k + 1), 64);
        pm[k].x = v[2 * k].x * mr0 + v[2 * k + 1].x * mr1;
        pm[k].y = v[2 * k].y * mr0 + v[2 * k + 1].y * mr1;
        pm[k].z = v[2 * k].z * mr0 + v[2 * k + 1].z * mr1;
        pm[k].w = v[2 * k].w * mr0 + v[2 * k + 1].w * mr1;
    }

    // ---- i2/i3/i4 via t[k] = pm[k]*pm[k+1] factorization ----
    float4 t[7];
#pragma unroll
    for (int k = 0; k < 7; ++k) {
        t[k].x = pm[k].x * pm[k + 1].x;
        t[k].y = pm[k].y * pm[k + 1].y;
        t[k].z = pm[k].z * pm[k + 1].z;
        t[k].w = pm[k].w * pm[k + 1].w;
    }
    float4 a2 = t[0];
#pragma unroll
    for (int k = 1; k < 7; ++k) {
        a2.x += t[k].x; a2.y += t[k].y; a2.z += t[k].z; a2.w += t[k].w;
    }
    float4 a3 = make_float4(0.f, 0.f, 0.f, 0.f);
#pragma unroll
    for (int k = 0; k < 6; ++k) {
        a3.x += t[k].x * pm[k + 2].x;
        a3.y += t[k].y * pm[k + 2].y;
        a3.z += t[k].z * pm[k + 2].z;
        a3.w += t[k].w * pm[k + 2].w;
    }
    float4 a4 = make_float4(0.f, 0.f, 0.f, 0.f);
#pragma unroll
    for (int k = 0; k < 5; ++k) {
        a4.x += t[k].x * t[k + 2].x;
        a4.y += t[k].y * t[k + 2].y;
        a4.z += t[k].z * t[k + 2].z;
        a4.w += t[k].w * t[k + 2].w;
    }
    a2.x *= (1.0f / 7.0f); a2.y *= (1.0f / 7.0f); a2.z *= (1.0f / 7.0f); a2.w *= (1.0f / 7.0f);
    a3.x *= (1.0f / 6.0f); a3.y *= (1.0f / 6.0f); a3.z *= (1.0f / 6.0f); a3.w *= (1.0f / 6.0f);
    a4.x *= (1.0f / 5.0f); a4.y *= (1.0f / 5.0f); a4.z *= (1.0f / 5.0f); a4.w *= (1.0f / 5.0f);
    float i2n = rnorm_fast(gred_sum16(dot4(a2, a2)));
    float i3n = rnorm_fast(gred_sum16(dot4(a3, a3)));
    float i4n = rnorm_fast(gred_sum16(dot4(a4, a4)));
    float4 pr;
    pr.x = (a2.x * i2n + a3.x * i3n + a4.x * i4n) * (1.0f / 3.0f);
    pr.y = (a2.y * i2n + a3.y * i3n + a4.y * i4n) * (1.0f / 3.0f);
    pr.z = (a2.z * i2n + a3.z * i3n + a4.z * i4n) * (1.0f / 3.0f);
    pr.w = (a2.w * i2n + a3.w * i3n + a4.w * i4n) * (1.0f / 3.0f);
    ((float4*)pr_sh[p])[j] = pr;
    __syncthreads();   // qf/rf written (wv<2 did it pre-consume) + pr_sh done

    {
        float4 q4 = ((const float4*)qf)[j];
        float4 r4 = ((const float4*)rf)[j];
        float4 h0 = ((const float4*)hw)[j];
        float4 h1 = ((const float4*)(hw + DD))[j];
        float w = -(q4.x - r4.x) * pr.x * h0.x + (q4.x * r4.x) * h1.x
                  - (q4.y - r4.y) * pr.y * h0.y + (q4.y * r4.y) * h1.y
                  - (q4.z - r4.z) * pr.z * h0.z + (q4.z * r4.z) * h1.z
                  - (q4.w - r4.w) * pr.w * h0.w + (q4.w * r4.w) * h1.w;
        w = gred_sum16(w);
        if (j == 0) weight_sh[p] = w;
    }
    __syncthreads();

    // ---- finale: wave 0 does softmax over P, pooled, scores ----
    if (wv == 0) {
        float wt = (weight_sh[lane] + hb[0]) * 5.0f;   // /0.2
        float mx = wt;
#pragma unroll
        for (int off = 32; off > 0; off >>= 1) mx = fmaxf(mx, __shfl_xor(mx, off, 64));
        float e = __expf(wt - mx);
        float wn = e / wred_sum(e);
        wsh[lane] = wn;
        float pooled = 0.f;
#pragma unroll 8
        for (int pp2 = 0; pp2 < PP; ++pp2) pooled += pr_sh[pp2][lane] * wsh[pp2];
        float qv = qf[lane], rv = rf[lane];
        float s1 = wred_sum(qv * rv * p1w[lane]);
        float s2 = wred_sum((rv - qv) * pooled * p2w[lane]);
        if (lane == 0) out[b] = (s1 + p1b[0]) + 5.0f * (s2 + p2b[0]);
    }
}

extern "C" void kernel_launch(void* const* d_in, const int* in_sizes, int n_in,
                              void* d_out, int out_size, void* d_ws, size_t ws_size,
                              hipStream_t stream) {
    const int*   qry_id = (const int*)d_in[0];
    const int*   res_id = (const int*)d_in[1];
    const int*   path   = (const int*)d_in[2];
    const int*   mask   = (const int*)d_in[3];
    const float* img    = (const float*)d_in[4];
    const float* Ww     = (const float*)d_in[5];
    const float* Wb     = (const float*)d_in[6];
    const float* meta   = (const float*)d_in[7];
    const float* hw     = (const float*)d_in[8];
    const float* hb     = (const float*)d_in[9];
    const float* p1w    = (const float*)d_in[10];
    const float* p1b    = (const float*)d_in[11];
    const float* p2w    = (const float*)d_in[12];
    const float* p2b    = (const float*)d_in[13];

    float* out = (float*)d_out;

    hipLaunchKernelGGL(k_fused, dim3(BB), dim3(1024), 0, stream,
                       qry_id, res_id, path, mask, img, Ww, Wb, meta,
                       hw, hb, p1w, p1b, p2w, p2b, out);
}